// Round 1
// baseline (330.497 us; speedup 1.0000x reference)
//
#include <hip/hip_runtime.h>

// Transformer block fwd: B=4, T=1024, C=1024, H=16, HS=64.
// All GEMMs bf16-MFMA (tolerance is 2% of max|ref| ~= 0.121), fp32 residuals.

typedef __bf16 bf16_t;
typedef __attribute__((ext_vector_type(8))) __bf16 bfx8;
typedef __attribute__((ext_vector_type(4))) __bf16 bfx4;
typedef __attribute__((ext_vector_type(4))) float f32x4;

#define MFMA_BF16(a, b, c) __builtin_amdgcn_mfma_f32_16x16x32_bf16((a), (b), (c), 0, 0, 0)
#define GLOAD_LDS16(g, l)                                                     \
  __builtin_amdgcn_global_load_lds((__attribute__((address_space(1))) void*)(g), \
                                   (__attribute__((address_space(3))) void*)(l), 16, 0, 0)

// ---------------- LayerNorm: fp32 in -> bf16 out ----------------
__global__ __launch_bounds__(256) void ln_kernel(const float* __restrict__ x,
                                                 const float* __restrict__ w,
                                                 const float* __restrict__ b,
                                                 bf16_t* __restrict__ out) {
  const int row = blockIdx.x;
  const int tid = threadIdx.x;
  const float4 v = reinterpret_cast<const float4*>(x + (size_t)row * 1024)[tid];
  float s = v.x + v.y + v.z + v.w;
  float s2 = v.x * v.x + v.y * v.y + v.z * v.z + v.w * v.w;
#pragma unroll
  for (int off = 1; off < 64; off <<= 1) {
    s += __shfl_xor(s, off);
    s2 += __shfl_xor(s2, off);
  }
  __shared__ float red[8];
  const int wv = tid >> 6;
  if ((tid & 63) == 0) {
    red[wv] = s;
    red[4 + wv] = s2;
  }
  __syncthreads();
  s = red[0] + red[1] + red[2] + red[3];
  s2 = red[4] + red[5] + red[6] + red[7];
  const float mu = s * (1.0f / 1024.0f);
  const float rs = rsqrtf(s2 * (1.0f / 1024.0f) - mu * mu + 1e-5f);
  const float4 wv4 = reinterpret_cast<const float4*>(w)[tid];
  const float4 bv4 = reinterpret_cast<const float4*>(b)[tid];
  bfx4 o;
  o[0] = (bf16_t)((v.x - mu) * rs * wv4.x + bv4.x);
  o[1] = (bf16_t)((v.y - mu) * rs * wv4.y + bv4.y);
  o[2] = (bf16_t)((v.z - mu) * rs * wv4.z + bv4.z);
  o[3] = (bf16_t)((v.w - mu) * rs * wv4.w + bv4.w);
  reinterpret_cast<bfx4*>(out + (size_t)row * 1024)[tid] = o;
}

// ---------------- Weight prep: fp32 [K,N]-ish -> bf16 B^T [N,K] ----------------
// WqkvT[n][c]: n in [0,1024)=Q, [1024,2048)=K, [2048,3072)=V; n%1024 = h*64+d
__global__ __launch_bounds__(256) void prep_qkvT(const float* __restrict__ Wq,
                                                 const float* __restrict__ Wk,
                                                 const float* __restrict__ Wv,
                                                 bf16_t* __restrict__ out) {
  const int o = blockIdx.x * 256 + threadIdx.x;  // 3072*1024
  const int n = o >> 10, c = o & 1023;
  const int sel = n >> 10;
  const int h = (n >> 6) & 15, d = n & 63;
  const float* src = (sel == 0) ? Wq : (sel == 1) ? Wk : Wv;
  out[o] = (bf16_t)src[((size_t)h * 1024 + c) * 64 + d];
}

// out[n][k] = W[k][n], W is [K=2^logK rows? no: W is [K, N] row-major]
__global__ __launch_bounds__(256) void prep_T(const float* __restrict__ W,
                                              bf16_t* __restrict__ out, int logK, int N) {
  const int o = blockIdx.x * 256 + threadIdx.x;  // N*K
  const int n = o >> logK, k = o & ((1 << logK) - 1);
  out[o] = (bf16_t)W[(size_t)k * N + n];
}

// ---------------- GEMM: C[M,N] = A[M,K](bf16) @ BT[N,K]^T (bf16) ----------------
// 128x128 tile, BK=64, 4 waves (each 64x64), mfma 16x16x32, global_load_lds w=16,
// XOR chunk swizzle (LDS linear dest, pre-swizzled global source, swizzled reads).
enum { EPI_QKV = 0, EPI_WO = 1, EPI_MLP1 = 2, EPI_FINAL = 3 };

template <int EPI>
__global__ __launch_bounds__(256) void gemm_bt(
    const bf16_t* __restrict__ A, const bf16_t* __restrict__ BT,
    const float* __restrict__ bias, const float* __restrict__ res,
    const float* __restrict__ prelu, float* __restrict__ outf,
    bf16_t* __restrict__ ob0, bf16_t* __restrict__ ob1, bf16_t* __restrict__ ob2,
    int K, int N) {
  __shared__ __align__(16) bf16_t sA[128 * 64];
  __shared__ __align__(16) bf16_t sB[128 * 64];
  const int tid = threadIdx.x;
  const int lane = tid & 63;
  const int w = tid >> 6;
  const int wr = w >> 1, wc = w & 1;
  const int row0 = blockIdx.x * 128, col0 = blockIdx.y * 128;

  f32x4 acc[4][4] = {};

  for (int k0 = 0; k0 < K; k0 += 64) {
    __syncthreads();
#pragma unroll
    for (int j = 0; j < 4; ++j) {
      const int chunk = j * 256 + tid;  // 1024 chunks of 16B per tile
      const int r = chunk >> 3, c = chunk & 7;
      const int cs = c ^ (r & 7);
      GLOAD_LDS16(A + (size_t)(row0 + r) * K + k0 + cs * 8, sA + chunk * 8);
      GLOAD_LDS16(BT + (size_t)(col0 + r) * K + k0 + cs * 8, sB + chunk * 8);
    }
    __syncthreads();
#pragma unroll
    for (int kk = 0; kk < 2; ++kk) {
      bfx8 af[4], bfr[4];
#pragma unroll
      for (int m = 0; m < 4; ++m) {
        const int r = wr * 64 + m * 16 + (lane & 15);
        const int c = (kk * 4 + (lane >> 4)) ^ (r & 7);
        af[m] = *reinterpret_cast<const bfx8*>(sA + r * 64 + c * 8);
      }
#pragma unroll
      for (int n = 0; n < 4; ++n) {
        const int r = wc * 64 + n * 16 + (lane & 15);
        const int c = (kk * 4 + (lane >> 4)) ^ (r & 7);
        bfr[n] = *reinterpret_cast<const bfx8*>(sB + r * 64 + c * 8);
      }
#pragma unroll
      for (int m = 0; m < 4; ++m)
#pragma unroll
        for (int n = 0; n < 4; ++n) acc[m][n] = MFMA_BF16(af[m], bfr[n], acc[m][n]);
    }
  }

  const float pa = (EPI == EPI_MLP1) ? prelu[0] : 0.0f;
#pragma unroll
  for (int m = 0; m < 4; ++m) {
#pragma unroll
    for (int n = 0; n < 4; ++n) {
#pragma unroll
      for (int j = 0; j < 4; ++j) {
        const int row = row0 + wr * 64 + m * 16 + ((lane >> 4) << 2) + j;
        const int col = col0 + wc * 64 + n * 16 + (lane & 15);
        const float v = acc[m][n][j];
        if (EPI == EPI_QKV) {
          const int sel = col >> 10;
          const int h = (col >> 6) & 15, d = col & 63;
          const int bb = row >> 10, t = row & 1023;
          bf16_t* dst = (sel == 0) ? ob0 : (sel == 1) ? ob1 : ob2;
          dst[((size_t)(bb * 16 + h) * 1024 + t) * 64 + d] = (bf16_t)v;
        } else if (EPI == EPI_MLP1) {
          float t = v + bias[col];
          t = (t > 0.0f) ? t : pa * t;
          ob0[(size_t)row * N + col] = (bf16_t)t;
        } else {  // EPI_WO / EPI_FINAL: out = v + bias + residual (fp32)
          outf[(size_t)row * N + col] = v + bias[col] + res[(size_t)row * N + col];
        }
      }
    }
  }
}

// ---------------- Causal flash attention ----------------
// scores[t][s] = k_t . q_s / 32, s <= t. "flash-Q" = k-proj rows, "flash-K" = q-proj.
// grid: (T/64, B*H). 4 waves; wave w owns rows t0+16w..+15. HS=64.
__global__ __launch_bounds__(256) void attn_kernel(const bf16_t* __restrict__ kproj,
                                                   const bf16_t* __restrict__ qproj,
                                                   const bf16_t* __restrict__ vproj,
                                                   bf16_t* __restrict__ att) {
  __shared__ __align__(16) bf16_t sQ[64 * 64];
  __shared__ __align__(16) bf16_t sK[64 * 64];
  __shared__ __align__(16) bf16_t sVt[64 * 64];  // V^T: [d][s]
  __shared__ __align__(16) bf16_t sP[4][16 * 64];
  const int tid = threadIdx.x, lane = tid & 63, w = tid >> 6;
  const int tb = blockIdx.x;
  const int bh = blockIdx.y;
  const size_t head = (size_t)bh * (1024 * 64);
  const int t0 = tb * 64;

#pragma unroll
  for (int j = 0; j < 2; ++j) {  // stage Q-tile (from k-proj), swizzled
    const int chunk = j * 256 + tid;
    const int r = chunk >> 3, c = chunk & 7;
    const int cs = c ^ (r & 7);
    GLOAD_LDS16(kproj + head + (size_t)(t0 + r) * 64 + cs * 8, sQ + chunk * 8);
  }

  f32x4 accO[4] = {};
  float mrun[4], lrun[4];
#pragma unroll
  for (int j = 0; j < 4; ++j) {
    mrun[j] = -1e30f;
    lrun[j] = 0.0f;
  }

  for (int sb = 0; sb <= tb; ++sb) {
    const int s0 = sb * 64;
    __syncthreads();  // prev iter done reading sK/sVt
#pragma unroll
    for (int j = 0; j < 2; ++j) {  // stage K-tile (from q-proj), swizzled
      const int chunk = j * 256 + tid;
      const int r = chunk >> 3, c = chunk & 7;
      const int cs = c ^ (r & 7);
      GLOAD_LDS16(qproj + head + (size_t)(s0 + r) * 64 + cs * 8, sK + chunk * 8);
    }
#pragma unroll
    for (int j = 0; j < 2; ++j) {  // stage V transposed (reg-staged), swizzled
      const int chunk = j * 256 + tid;
      const int s = chunk >> 3, db = chunk & 7;
      const bfx8 vv =
          *reinterpret_cast<const bfx8*>(vproj + head + (size_t)(s0 + s) * 64 + db * 8);
#pragma unroll
      for (int i = 0; i < 8; ++i) {
        const int d = db * 8 + i;
        const int cc = (s >> 3) ^ (d & 7);
        sVt[d * 64 + cc * 8 + (s & 7)] = vv[i];
      }
    }
    __syncthreads();

    // S = Qf @ Kf^T  (wave: 16 rows x 64 cols)
    f32x4 accS[4] = {};
#pragma unroll
    for (int kk = 0; kk < 2; ++kk) {
      bfx8 aq;
      {
        const int r = w * 16 + (lane & 15);
        const int c = (kk * 4 + (lane >> 4)) ^ (r & 7);
        aq = *reinterpret_cast<const bfx8*>(sQ + r * 64 + c * 8);
      }
#pragma unroll
      for (int n = 0; n < 4; ++n) {
        const int r = n * 16 + (lane & 15);
        const int c = (kk * 4 + (lane >> 4)) ^ (r & 7);
        const bfx8 bk = *reinterpret_cast<const bfx8*>(sK + r * 64 + c * 8);
        accS[n] = MFMA_BF16(aq, bk, accS[n]);
      }
    }

    // online softmax (rows live in 16-lane groups; lane holds rows (lane>>4)*4+j)
    const int rbase = t0 + w * 16 + ((lane >> 4) << 2);
    const int cbase = s0 + (lane & 15);
#pragma unroll
    for (int j = 0; j < 4; ++j) {
      const int t = rbase + j;
      float mx = -1e30f;
#pragma unroll
      for (int n = 0; n < 4; ++n) {
        float v = accS[n][j] * 0.03125f;
        v = ((cbase + n * 16) <= t) ? v : -1e30f;
        accS[n][j] = v;
        mx = fmaxf(mx, v);
      }
      mx = fmaxf(mx, __shfl_xor(mx, 1));
      mx = fmaxf(mx, __shfl_xor(mx, 2));
      mx = fmaxf(mx, __shfl_xor(mx, 4));
      mx = fmaxf(mx, __shfl_xor(mx, 8));
      const float mnew = fmaxf(mrun[j], mx);
      const float al = __expf(mrun[j] - mnew);
      float rsum = 0.0f;
#pragma unroll
      for (int n = 0; n < 4; ++n) {
        const float p = __expf(accS[n][j] - mnew);
        accS[n][j] = p;
        rsum += p;
      }
      rsum += __shfl_xor(rsum, 1);
      rsum += __shfl_xor(rsum, 2);
      rsum += __shfl_xor(rsum, 4);
      rsum += __shfl_xor(rsum, 8);
      lrun[j] = lrun[j] * al + rsum;
      mrun[j] = mnew;
#pragma unroll
      for (int n = 0; n < 4; ++n) accO[n][j] *= al;
    }

    // P -> bf16 via per-wave LDS (A-fragment transpose), swizzled
    bf16_t* sPw = sP[w];
#pragma unroll
    for (int n = 0; n < 4; ++n)
#pragma unroll
      for (int j = 0; j < 4; ++j) {
        const int r = ((lane >> 4) << 2) + j;
        const int s = n * 16 + (lane & 15);
        const int cc = (s >> 3) ^ (r & 7);
        sPw[r * 64 + cc * 8 + (s & 7)] = (bf16_t)accS[n][j];
      }

    // O += P @ V
#pragma unroll
    for (int kk = 0; kk < 2; ++kk) {
      bfx8 ap;
      {
        const int r = lane & 15;
        const int c = (kk * 4 + (lane >> 4)) ^ (r & 7);
        ap = *reinterpret_cast<const bfx8*>(sPw + r * 64 + c * 8);
      }
#pragma unroll
      for (int n = 0; n < 4; ++n) {
        const int d = n * 16 + (lane & 15);
        const int c = (kk * 4 + (lane >> 4)) ^ (d & 7);
        const bfx8 bv = *reinterpret_cast<const bfx8*>(sVt + d * 64 + c * 8);
        accO[n] = MFMA_BF16(ap, bv, accO[n]);
      }
    }
  }

  const int b = bh >> 4, h = bh & 15;
#pragma unroll
  for (int j = 0; j < 4; ++j) {
    const float inv = 1.0f / lrun[j];
    const int t = t0 + w * 16 + ((lane >> 4) << 2) + j;
#pragma unroll
    for (int n = 0; n < 4; ++n) {
      const int d = n * 16 + (lane & 15);
      att[((size_t)(b * 1024 + t)) * 1024 + h * 64 + d] = (bf16_t)(accO[n][j] * inv);
    }
  }
}

extern "C" void kernel_launch(void* const* d_in, const int* in_sizes, int n_in,
                              void* d_out, int out_size, void* d_ws, size_t ws_size,
                              hipStream_t stream) {
  (void)in_sizes; (void)n_in; (void)out_size; (void)ws_size;
  const float* x = (const float*)d_in[0];
  const float* ln1w = (const float*)d_in[1];
  const float* ln1b = (const float*)d_in[2];
  const float* Wk = (const float*)d_in[3];
  const float* Wq = (const float*)d_in[4];
  const float* Wv = (const float*)d_in[5];
  const float* Wo = (const float*)d_in[6];
  const float* bo = (const float*)d_in[7];
  const float* ln2w = (const float*)d_in[8];
  const float* ln2b = (const float*)d_in[9];
  const float* W1 = (const float*)d_in[10];
  const float* b1 = (const float*)d_in[11];
  const float* pa = (const float*)d_in[12];
  const float* W2 = (const float*)d_in[13];
  const float* b2 = (const float*)d_in[14];
  float* out = (float*)d_out;
  char* ws = (char*)d_ws;
  const size_t MB = 1ull << 20;
  bf16_t* h1 = (bf16_t*)(ws + 0 * MB);      // [4096,1024]
  bf16_t* h2 = (bf16_t*)(ws + 8 * MB);      // [4096,1024]
  bf16_t* qb = (bf16_t*)(ws + 16 * MB);     // [B*H,1024,64]
  bf16_t* kb = (bf16_t*)(ws + 24 * MB);
  bf16_t* vb = (bf16_t*)(ws + 32 * MB);
  bf16_t* attb = (bf16_t*)(ws + 40 * MB);   // [4096,1024]
  bf16_t* fbuf = (bf16_t*)(ws + 48 * MB);   // [4096,4096]
  bf16_t* WqkvT = (bf16_t*)(ws + 80 * MB);  // [3072,1024]
  bf16_t* WoT = (bf16_t*)(ws + 86 * MB);    // [1024,1024]
  bf16_t* W1T = (bf16_t*)(ws + 88 * MB);    // [4096,1024]
  bf16_t* W2T = (bf16_t*)(ws + 96 * MB);    // [1024,4096]

  prep_qkvT<<<12288, 256, 0, stream>>>(Wq, Wk, Wv, WqkvT);
  prep_T<<<4096, 256, 0, stream>>>(Wo, WoT, 10, 1024);
  prep_T<<<16384, 256, 0, stream>>>(W1, W1T, 10, 4096);
  prep_T<<<16384, 256, 0, stream>>>(W2, W2T, 12, 1024);

  ln_kernel<<<4096, 256, 0, stream>>>(x, ln1w, ln1b, h1);
  gemm_bt<EPI_QKV><<<dim3(32, 24), 256, 0, stream>>>(h1, WqkvT, nullptr, nullptr, nullptr,
                                                     nullptr, qb, kb, vb, 1024, 3072);
  attn_kernel<<<dim3(16, 64), 256, 0, stream>>>(kb, qb, vb, attb);
  gemm_bt<EPI_WO><<<dim3(32, 8), 256, 0, stream>>>(attb, WoT, bo, x, nullptr, out, nullptr,
                                                   nullptr, nullptr, 1024, 1024);
  ln_kernel<<<4096, 256, 0, stream>>>(out, ln2w, ln2b, h2);
  gemm_bt<EPI_MLP1><<<dim3(32, 32), 256, 0, stream>>>(h2, W1T, b1, nullptr, pa, nullptr,
                                                      fbuf, nullptr, nullptr, 1024, 4096);
  gemm_bt<EPI_FINAL><<<dim3(32, 8), 256, 0, stream>>>(fbuf, W2T, b2, out, nullptr, out,
                                                      nullptr, nullptr, nullptr, 4096, 1024);
}

// Round 2
// 238.274 us; speedup vs baseline: 1.3870x; 1.3870x over previous
//
#include <hip/hip_runtime.h>

// Transformer block fwd: B=4, T=1024, C=1024, H=16, HS=64.
// bf16 MFMA GEMMs + flash attention; fp32 residual path.

typedef __bf16 bf16_t;
typedef __attribute__((ext_vector_type(8))) __bf16 bfx8;
typedef __attribute__((ext_vector_type(4))) __bf16 bfx4;
typedef __attribute__((ext_vector_type(4))) float f32x4;
typedef __attribute__((ext_vector_type(8))) unsigned short u16x8;
typedef unsigned int u32;

#define MFMA_BF16(a, b, c) __builtin_amdgcn_mfma_f32_16x16x32_bf16((a), (b), (c), 0, 0, 0)
#define GLOAD_LDS16(g, l)                                                     \
  __builtin_amdgcn_global_load_lds((__attribute__((address_space(1))) void*)(g), \
                                   (__attribute__((address_space(3))) void*)(l), 16, 0, 0)

// ---------------- LayerNorm: fp32 in -> bf16 out ----------------
__global__ __launch_bounds__(256) void ln_kernel(const float* __restrict__ x,
                                                 const float* __restrict__ w,
                                                 const float* __restrict__ b,
                                                 bf16_t* __restrict__ out) {
  const int row = blockIdx.x;
  const int tid = threadIdx.x;
  const float4 v = reinterpret_cast<const float4*>(x + (size_t)row * 1024)[tid];
  float s = v.x + v.y + v.z + v.w;
  float s2 = v.x * v.x + v.y * v.y + v.z * v.z + v.w * v.w;
#pragma unroll
  for (int off = 1; off < 64; off <<= 1) {
    s += __shfl_xor(s, off);
    s2 += __shfl_xor(s2, off);
  }
  __shared__ float red[8];
  const int wv = tid >> 6;
  if ((tid & 63) == 0) {
    red[wv] = s;
    red[4 + wv] = s2;
  }
  __syncthreads();
  s = red[0] + red[1] + red[2] + red[3];
  s2 = red[4] + red[5] + red[6] + red[7];
  const float mu = s * (1.0f / 1024.0f);
  const float rs = rsqrtf(s2 * (1.0f / 1024.0f) - mu * mu + 1e-5f);
  const float4 wv4 = reinterpret_cast<const float4*>(w)[tid];
  const float4 bv4 = reinterpret_cast<const float4*>(b)[tid];
  bfx4 o;
  o[0] = (bf16_t)((v.x - mu) * rs * wv4.x + bv4.x);
  o[1] = (bf16_t)((v.y - mu) * rs * wv4.y + bv4.y);
  o[2] = (bf16_t)((v.z - mu) * rs * wv4.z + bv4.z);
  o[3] = (bf16_t)((v.w - mu) * rs * wv4.w + bv4.w);
  reinterpret_cast<bfx4*>(out + (size_t)row * 1024)[tid] = o;
}

// ---------------- Tiled transpose+cast: fp32 [K,N] -> bf16 [N,K] (batched) ----
__global__ __launch_bounds__(256) void transpose_cast(const float* __restrict__ in,
                                                      bf16_t* __restrict__ out, int K, int N,
                                                      long in_bstride, long out_bstride) {
  __shared__ float tile[64][65];
  const int z = blockIdx.z;
  in += (long)z * in_bstride;
  out += (long)z * out_bstride;
  const int k0 = blockIdx.x * 64, n0 = blockIdx.y * 64;
  const int t = threadIdx.x;
  const int rl = t >> 4, cl = (t & 15) * 4;
#pragma unroll
  for (int p = 0; p < 4; ++p) {
    const int r = p * 16 + rl;
    const float4 v = *reinterpret_cast<const float4*>(in + (size_t)(k0 + r) * N + n0 + cl);
    tile[r][cl] = v.x;
    tile[r][cl + 1] = v.y;
    tile[r][cl + 2] = v.z;
    tile[r][cl + 3] = v.w;
  }
  __syncthreads();
#pragma unroll
  for (int p = 0; p < 2; ++p) {
    const int idx = p * 256 + t;
    const int n = idx >> 3, kc = (idx & 7) * 8;
    bfx8 o;
#pragma unroll
    for (int i = 0; i < 8; ++i) o[i] = (bf16_t)tile[kc + i][n];
    *reinterpret_cast<bfx8*>(out + (size_t)(n0 + n) * K + k0 + kc) = o;
  }
}

// ---------------- GEMM: C[M,N] = A[M,K](bf16) @ BT[N,K]^T (bf16) ----------------
enum { EPI_QKV = 0, EPI_WO = 1, EPI_MLP1 = 2, EPI_FINAL = 3 };

template <int EPI, int BM>
__global__ __launch_bounds__(256) void gemm_bt(
    const bf16_t* __restrict__ A, const bf16_t* __restrict__ BT,
    const float* __restrict__ bias, const float* __restrict__ res,
    const float* __restrict__ prelu, float* __restrict__ outf,
    bf16_t* __restrict__ ob0, bf16_t* __restrict__ ob1, bf16_t* __restrict__ ob2,
    int K, int N) {
  __shared__ __align__(16) bf16_t sA[BM * 64];
  __shared__ __align__(16) bf16_t sB[128 * 64];
  const int tid = threadIdx.x;
  const int lane = tid & 63;
  const int w = tid >> 6;
  const int wr = w >> 1, wc = w & 1;
  const int row0 = blockIdx.x * BM, col0 = blockIdx.y * 128;
  constexpr int MF = BM / 32;  // m-fragments per wave

  f32x4 acc[MF][4] = {};

  for (int k0 = 0; k0 < K; k0 += 64) {
    __syncthreads();
#pragma unroll
    for (int j = 0; j < MF; ++j) {
      const int chunk = j * 256 + tid;
      const int r = chunk >> 3, c = chunk & 7;
      const int cs = c ^ (r & 7);
      GLOAD_LDS16(A + (size_t)(row0 + r) * K + k0 + cs * 8, sA + chunk * 8);
    }
#pragma unroll
    for (int j = 0; j < 4; ++j) {
      const int chunk = j * 256 + tid;
      const int r = chunk >> 3, c = chunk & 7;
      const int cs = c ^ (r & 7);
      GLOAD_LDS16(BT + (size_t)(col0 + r) * K + k0 + cs * 8, sB + chunk * 8);
    }
    __syncthreads();
#pragma unroll
    for (int kk = 0; kk < 2; ++kk) {
      bfx8 af[MF], bfr[4];
#pragma unroll
      for (int m = 0; m < MF; ++m) {
        const int r = wr * (BM / 2) + m * 16 + (lane & 15);
        const int c = (kk * 4 + (lane >> 4)) ^ (r & 7);
        af[m] = *reinterpret_cast<const bfx8*>(sA + r * 64 + c * 8);
      }
#pragma unroll
      for (int n = 0; n < 4; ++n) {
        const int r = wc * 64 + n * 16 + (lane & 15);
        const int c = (kk * 4 + (lane >> 4)) ^ (r & 7);
        bfr[n] = *reinterpret_cast<const bfx8*>(sB + r * 64 + c * 8);
      }
#pragma unroll
      for (int m = 0; m < MF; ++m)
#pragma unroll
        for (int n = 0; n < 4; ++n) acc[m][n] = MFMA_BF16(af[m], bfr[n], acc[m][n]);
    }
  }

  const float pa = (EPI == EPI_MLP1) ? prelu[0] : 0.0f;
#pragma unroll
  for (int m = 0; m < MF; ++m) {
#pragma unroll
    for (int n = 0; n < 4; ++n) {
#pragma unroll
      for (int j = 0; j < 4; ++j) {
        const int row = row0 + wr * (BM / 2) + m * 16 + ((lane >> 4) << 2) + j;
        const int col = col0 + wc * 64 + n * 16 + (lane & 15);
        const float v = acc[m][n][j];
        if (EPI == EPI_QKV) {
          const int sel = col >> 10;
          const int h = (col >> 6) & 15, d = col & 63;
          const int bb = row >> 10, t = row & 1023;
          bf16_t* dst = (sel == 0) ? ob0 : (sel == 1) ? ob1 : ob2;
          dst[((size_t)(bb * 16 + h) * 1024 + t) * 64 + d] = (bf16_t)v;
        } else if (EPI == EPI_MLP1) {
          float t = v + bias[col];
          t = (t > 0.0f) ? t : pa * t;
          ob0[(size_t)row * N + col] = (bf16_t)t;
        } else {  // EPI_WO / EPI_FINAL
          outf[(size_t)row * N + col] = v + bias[col] + res[(size_t)row * N + col];
        }
      }
    }
  }
}

// ---------------- Causal flash attention ----------------
// scores[t][s] = k_t . q_s / 32, s <= t. t-side rows = kproj, s-side = qproj.
// grid: (8, B*H). Block handles t-blocks {bx, 15-bx} sequentially (17 s-iters total).
// Double-buffered K (global_load_lds) and V^T (reg-staged, write-late). 1 barrier/iter.
__global__ __launch_bounds__(256) void attn_kernel(const bf16_t* __restrict__ kproj,
                                                   const bf16_t* __restrict__ qproj,
                                                   const bf16_t* __restrict__ vproj,
                                                   bf16_t* __restrict__ att) {
  __shared__ __align__(16) bf16_t sK[2][64 * 64];
  __shared__ __align__(16) bf16_t sVt[2][64 * 64];
  __shared__ __align__(16) bf16_t sP[4][16 * 64];
  const int tid = threadIdx.x, lane = tid & 63, w = tid >> 6;
  const int g = lane >> 4, l15 = lane & 15;
  const int bh = blockIdx.y;
  const size_t head = (size_t)bh * (1024 * 64);
  const int b = bh >> 4, h = bh & 15;
  const int vrow = 2 * (tid >> 3);  // V staging: even s-row this thread handles
  const int vdb = tid & 7;          // d-chunk (8 bf16)

  for (int half = 0; half < 2; ++half) {
    const int tb = half ? (15 - (int)blockIdx.x) : (int)blockIdx.x;
    const int t0 = tb * 64;
    const int nsb = tb + 1;

    __syncthreads();  // previous half's buffers fully consumed

    // Q fragments straight from global (each lane reads its own row chunks)
    bfx8 aq0, aq1;
    {
      const bf16_t* qrow = kproj + head + (size_t)(t0 + w * 16 + l15) * 64 + g * 8;
      aq0 = *reinterpret_cast<const bfx8*>(qrow);
      aq1 = *reinterpret_cast<const bfx8*>(qrow + 32);
    }

    // prologue: stage sb=0 into buffer 0
    {
#pragma unroll
      for (int j = 0; j < 2; ++j) {
        const int chunk = j * 256 + tid;
        const int r = chunk >> 3, c = chunk & 7;
        const int cs = c ^ (r & 7);
        GLOAD_LDS16(qproj + head + (size_t)r * 64 + cs * 8, sK[0] + chunk * 8);
      }
      const bf16_t* vp = vproj + head + (size_t)vrow * 64 + vdb * 8;
      const u16x8 v0 = *reinterpret_cast<const u16x8*>(vp);
      const u16x8 v1 = *reinterpret_cast<const u16x8*>(vp + 64);
#pragma unroll
      for (int i = 0; i < 8; ++i) {
        const int d = vdb * 8 + i;
        const int cc = ((vrow >> 3) ^ i ^ vdb) & 7;
        const u32 pk = ((u32)v1[i] << 16) | (u32)v0[i];
        *reinterpret_cast<u32*>(sVt[0] + d * 64 + cc * 8 + (vrow & 7)) = pk;
      }
    }
    __syncthreads();

    f32x4 accO[4] = {};
    float mrun[4], lrun[4];
#pragma unroll
    for (int j = 0; j < 4; ++j) {
      mrun[j] = -1e30f;
      lrun[j] = 0.0f;
    }

    for (int sb = 0; sb < nsb; ++sb) {
      const int cur = sb & 1;
      const bool pf = (sb + 1 < nsb);
      u16x8 v0n, v1n;
      if (pf) {  // issue next-tile loads early (latency hides under compute)
        const int s0n = (sb + 1) * 64;
#pragma unroll
        for (int j = 0; j < 2; ++j) {
          const int chunk = j * 256 + tid;
          const int r = chunk >> 3, c = chunk & 7;
          const int cs = c ^ (r & 7);
          GLOAD_LDS16(qproj + head + (size_t)(s0n + r) * 64 + cs * 8, sK[cur ^ 1] + chunk * 8);
        }
        const bf16_t* vp = vproj + head + (size_t)(s0n + vrow) * 64 + vdb * 8;
        v0n = *reinterpret_cast<const u16x8*>(vp);
        v1n = *reinterpret_cast<const u16x8*>(vp + 64);
      }

      // S = Q @ K^T  (wave: 16 t-rows x 64 s-cols)
      f32x4 accS[4] = {};
      const bf16_t* sKc = sK[cur];
#pragma unroll
      for (int kk = 0; kk < 2; ++kk) {
        const bfx8 aq = kk ? aq1 : aq0;
#pragma unroll
        for (int n = 0; n < 4; ++n) {
          const int r = n * 16 + l15;
          const int c = (kk * 4 + g) ^ (r & 7);
          const bfx8 bk = *reinterpret_cast<const bfx8*>(sKc + r * 64 + c * 8);
          accS[n] = MFMA_BF16(aq, bk, accS[n]);
        }
      }

      // online softmax
      const int rbase = t0 + w * 16 + (g << 2);
      const int cbase = sb * 64 + l15;
#pragma unroll
      for (int j = 0; j < 4; ++j) {
        const int t = rbase + j;
        float mx = -1e30f;
#pragma unroll
        for (int n = 0; n < 4; ++n) {
          float v = accS[n][j] * 0.03125f;
          v = ((cbase + n * 16) <= t) ? v : -1e30f;
          accS[n][j] = v;
          mx = fmaxf(mx, v);
        }
        mx = fmaxf(mx, __shfl_xor(mx, 1));
        mx = fmaxf(mx, __shfl_xor(mx, 2));
        mx = fmaxf(mx, __shfl_xor(mx, 4));
        mx = fmaxf(mx, __shfl_xor(mx, 8));
        const float mnew = fmaxf(mrun[j], mx);
        const float al = __expf(mrun[j] - mnew);
        float rsum = 0.0f;
#pragma unroll
        for (int n = 0; n < 4; ++n) {
          const float p = __expf(accS[n][j] - mnew);
          accS[n][j] = p;
          rsum += p;
        }
        rsum += __shfl_xor(rsum, 1);
        rsum += __shfl_xor(rsum, 2);
        rsum += __shfl_xor(rsum, 4);
        rsum += __shfl_xor(rsum, 8);
        lrun[j] = lrun[j] * al + rsum;
        mrun[j] = mnew;
#pragma unroll
        for (int n = 0; n < 4; ++n) accO[n][j] *= al;
      }

      // P -> bf16 via per-wave LDS (A-fragment transpose)
      bf16_t* sPw = sP[w];
#pragma unroll
      for (int n = 0; n < 4; ++n)
#pragma unroll
        for (int j = 0; j < 4; ++j) {
          const int r = (g << 2) + j;
          const int s = n * 16 + l15;
          const int cc = (s >> 3) ^ (r & 7);
          sPw[r * 64 + cc * 8 + (s & 7)] = (bf16_t)accS[n][j];
        }

      // O += P @ V
      const bf16_t* sVc = sVt[cur];
#pragma unroll
      for (int kk = 0; kk < 2; ++kk) {
        bfx8 ap;
        {
          const int r = l15;
          const int c = (kk * 4 + g) ^ (r & 7);
          ap = *reinterpret_cast<const bfx8*>(sPw + r * 64 + c * 8);
        }
#pragma unroll
        for (int n = 0; n < 4; ++n) {
          const int d = n * 16 + l15;
          const int c = (kk * 4 + g) ^ (d & 7) ^ ((d >> 3) & 7);
          const bfx8 bv = *reinterpret_cast<const bfx8*>(sVc + d * 64 + c * 8);
          accO[n] = MFMA_BF16(ap, bv, accO[n]);
        }
      }

      if (pf) {  // write-late V^T staging into the other buffer
#pragma unroll
        for (int i = 0; i < 8; ++i) {
          const int d = vdb * 8 + i;
          const int cc = ((vrow >> 3) ^ i ^ vdb) & 7;
          const u32 pk = ((u32)v1n[i] << 16) | (u32)v0n[i];
          *reinterpret_cast<u32*>(sVt[cur ^ 1] + d * 64 + cc * 8 + (vrow & 7)) = pk;
        }
      }
      __syncthreads();
    }

    // epilogue: normalize + write this half's output
#pragma unroll
    for (int j = 0; j < 4; ++j) {
      const float inv = 1.0f / lrun[j];
      const int t = t0 + w * 16 + (g << 2) + j;
#pragma unroll
      for (int n = 0; n < 4; ++n) {
        const int d = n * 16 + l15;
        att[((size_t)(b * 1024 + t)) * 1024 + h * 64 + d] = (bf16_t)(accO[n][j] * inv);
      }
    }
  }
}

extern "C" void kernel_launch(void* const* d_in, const int* in_sizes, int n_in,
                              void* d_out, int out_size, void* d_ws, size_t ws_size,
                              hipStream_t stream) {
  (void)in_sizes; (void)n_in; (void)out_size; (void)ws_size;
  const float* x = (const float*)d_in[0];
  const float* ln1w = (const float*)d_in[1];
  const float* ln1b = (const float*)d_in[2];
  const float* Wk = (const float*)d_in[3];
  const float* Wq = (const float*)d_in[4];
  const float* Wv = (const float*)d_in[5];
  const float* Wo = (const float*)d_in[6];
  const float* bo = (const float*)d_in[7];
  const float* ln2w = (const float*)d_in[8];
  const float* ln2b = (const float*)d_in[9];
  const float* W1 = (const float*)d_in[10];
  const float* b1 = (const float*)d_in[11];
  const float* pa = (const float*)d_in[12];
  const float* W2 = (const float*)d_in[13];
  const float* b2 = (const float*)d_in[14];
  float* out = (float*)d_out;
  char* ws = (char*)d_ws;
  const size_t MB = 1ull << 20;
  bf16_t* h1 = (bf16_t*)(ws + 0 * MB);      // [4096,1024]
  bf16_t* h2 = (bf16_t*)(ws + 8 * MB);      // [4096,1024]
  bf16_t* qb = (bf16_t*)(ws + 16 * MB);     // [B*H,1024,64]
  bf16_t* kb = (bf16_t*)(ws + 24 * MB);
  bf16_t* vb = (bf16_t*)(ws + 32 * MB);
  bf16_t* attb = (bf16_t*)(ws + 40 * MB);   // [4096,1024]
  bf16_t* fbuf = (bf16_t*)(ws + 48 * MB);   // [4096,4096]
  bf16_t* WqkvT = (bf16_t*)(ws + 80 * MB);  // [3072,1024]
  bf16_t* WoT = (bf16_t*)(ws + 86 * MB);    // [1024,1024]
  bf16_t* W1T = (bf16_t*)(ws + 88 * MB);    // [4096,1024]
  bf16_t* W2T = (bf16_t*)(ws + 96 * MB);    // [1024,4096]

  // Weight prep (coalesced tiled transpose+cast)
  transpose_cast<<<dim3(16, 1, 16), 256, 0, stream>>>(Wq, WqkvT, 1024, 64, 65536, 65536);
  transpose_cast<<<dim3(16, 1, 16), 256, 0, stream>>>(Wk, WqkvT + (1024 * 1024), 1024, 64,
                                                      65536, 65536);
  transpose_cast<<<dim3(16, 1, 16), 256, 0, stream>>>(Wv, WqkvT + (2048 * 1024), 1024, 64,
                                                      65536, 65536);
  transpose_cast<<<dim3(16, 16, 1), 256, 0, stream>>>(Wo, WoT, 1024, 1024, 0, 0);
  transpose_cast<<<dim3(16, 64, 1), 256, 0, stream>>>(W1, W1T, 1024, 4096, 0, 0);
  transpose_cast<<<dim3(64, 16, 1), 256, 0, stream>>>(W2, W2T, 4096, 1024, 0, 0);

  ln_kernel<<<4096, 256, 0, stream>>>(x, ln1w, ln1b, h1);
  gemm_bt<EPI_QKV, 128><<<dim3(32, 24), 256, 0, stream>>>(h1, WqkvT, nullptr, nullptr,
                                                          nullptr, nullptr, qb, kb, vb,
                                                          1024, 3072);
  attn_kernel<<<dim3(8, 64), 256, 0, stream>>>(kb, qb, vb, attb);
  gemm_bt<EPI_WO, 64><<<dim3(64, 8), 256, 0, stream>>>(attb, WoT, bo, x, nullptr, out,
                                                       nullptr, nullptr, nullptr, 1024, 1024);
  ln_kernel<<<4096, 256, 0, stream>>>(out, ln2w, ln2b, h2);
  gemm_bt<EPI_MLP1, 128><<<dim3(32, 32), 256, 0, stream>>>(h2, W1T, b1, nullptr, pa, nullptr,
                                                           fbuf, nullptr, nullptr, 1024, 4096);
  gemm_bt<EPI_FINAL, 64><<<dim3(64, 8), 256, 0, stream>>>(fbuf, W2T, b2, out, nullptr, out,
                                                          nullptr, nullptr, nullptr, 4096, 1024);
}

// Round 3
// 227.141 us; speedup vs baseline: 1.4550x; 1.0490x over previous
//
#include <hip/hip_runtime.h>

// Transformer block fwd: B=4, T=1024, C=1024, H=16, HS=64.
// bf16 MFMA GEMMs (double-buffered 2-phase) + flash attention; fp32 residual path.

typedef __bf16 bf16_t;
typedef __attribute__((ext_vector_type(8))) __bf16 bfx8;
typedef __attribute__((ext_vector_type(4))) __bf16 bfx4;
typedef __attribute__((ext_vector_type(4))) float f32x4;
typedef __attribute__((ext_vector_type(8))) unsigned short u16x8;
typedef unsigned int u32;

#define MFMA_BF16(a, b, c) __builtin_amdgcn_mfma_f32_16x16x32_bf16((a), (b), (c), 0, 0, 0)
#define GLOAD_LDS16(g, l)                                                     \
  __builtin_amdgcn_global_load_lds((__attribute__((address_space(1))) void*)(g), \
                                   (__attribute__((address_space(3))) void*)(l), 16, 0, 0)

// ---------------- LayerNorm: fp32 in -> bf16 out ----------------
__global__ __launch_bounds__(256) void ln_kernel(const float* __restrict__ x,
                                                 const float* __restrict__ w,
                                                 const float* __restrict__ b,
                                                 bf16_t* __restrict__ out) {
  const int row = blockIdx.x;
  const int tid = threadIdx.x;
  const float4 v = reinterpret_cast<const float4*>(x + (size_t)row * 1024)[tid];
  float s = v.x + v.y + v.z + v.w;
  float s2 = v.x * v.x + v.y * v.y + v.z * v.z + v.w * v.w;
#pragma unroll
  for (int off = 1; off < 64; off <<= 1) {
    s += __shfl_xor(s, off);
    s2 += __shfl_xor(s2, off);
  }
  __shared__ float red[8];
  const int wv = tid >> 6;
  if ((tid & 63) == 0) {
    red[wv] = s;
    red[4 + wv] = s2;
  }
  __syncthreads();
  s = red[0] + red[1] + red[2] + red[3];
  s2 = red[4] + red[5] + red[6] + red[7];
  const float mu = s * (1.0f / 1024.0f);
  const float rs = rsqrtf(s2 * (1.0f / 1024.0f) - mu * mu + 1e-5f);
  const float4 wv4 = reinterpret_cast<const float4*>(w)[tid];
  const float4 bv4 = reinterpret_cast<const float4*>(b)[tid];
  bfx4 o;
  o[0] = (bf16_t)((v.x - mu) * rs * wv4.x + bv4.x);
  o[1] = (bf16_t)((v.y - mu) * rs * wv4.y + bv4.y);
  o[2] = (bf16_t)((v.z - mu) * rs * wv4.z + bv4.z);
  o[3] = (bf16_t)((v.w - mu) * rs * wv4.w + bv4.w);
  reinterpret_cast<bfx4*>(out + (size_t)row * 1024)[tid] = o;
}

// ---------------- Tiled transpose+cast: fp32 [K,N] -> bf16 [N,K] ----------------
__device__ __forceinline__ void tc_body(const float* __restrict__ in,
                                        bf16_t* __restrict__ out, int K, int N, int k0,
                                        int n0, float (*tile)[65], int t) {
  const int rl = t >> 4, cl = (t & 15) * 4;
#pragma unroll
  for (int p = 0; p < 4; ++p) {
    const int r = p * 16 + rl;
    const float4 v = *reinterpret_cast<const float4*>(in + (size_t)(k0 + r) * N + n0 + cl);
    tile[r][cl] = v.x;
    tile[r][cl + 1] = v.y;
    tile[r][cl + 2] = v.z;
    tile[r][cl + 3] = v.w;
  }
  __syncthreads();
#pragma unroll
  for (int p = 0; p < 2; ++p) {
    const int idx = p * 256 + t;
    const int n = idx >> 3, kc = (idx & 7) * 8;
    bfx8 o;
#pragma unroll
    for (int i = 0; i < 8; ++i) o[i] = (bf16_t)tile[kc + i][n];
    *reinterpret_cast<bfx8*>(out + (size_t)(n0 + n) * K + k0 + kc) = o;
  }
}

__global__ __launch_bounds__(256) void transpose_cast(const float* __restrict__ in,
                                                      bf16_t* __restrict__ out, int K,
                                                      int N) {
  __shared__ float tile[64][65];
  tc_body(in, out, K, N, blockIdx.x * 64, blockIdx.y * 64, tile, threadIdx.x);
}

// q/k/v weights: [H,1024,64] fp32 -> [1024 n][1024 c] bf16 per matrix, concatenated.
__global__ __launch_bounds__(256) void transpose_qkv(const float* __restrict__ Wq,
                                                     const float* __restrict__ Wk,
                                                     const float* __restrict__ Wv,
                                                     bf16_t* __restrict__ out) {
  __shared__ float tile[64][65];
  const int z = blockIdx.y;  // 0..47
  const int sel = z >> 4, h = z & 15;
  const float* in = ((sel == 0) ? Wq : (sel == 1) ? Wk : Wv) + h * 65536;
  bf16_t* o = out + (size_t)sel * 1048576 + h * 65536;
  tc_body(in, o, 1024, 64, blockIdx.x * 64, 0, tile, threadIdx.x);
}

// ---------------- GEMM: C[M,N] = A[M,K](bf16) @ BT[N,K]^T (bf16) ----------------
// 2-phase double-buffered: stage(next) issued before compute(cur); 1 barrier/K-step.
enum { EPI_QKV = 0, EPI_WO = 1, EPI_MLP1 = 2, EPI_FINAL = 3 };

template <int MF>
__device__ __forceinline__ void stage_tile(const bf16_t* __restrict__ A,
                                           const bf16_t* __restrict__ BT, int K, int row0,
                                           int col0, int k0, bf16_t* sA, bf16_t* sB,
                                           int tid) {
#pragma unroll
  for (int j = 0; j < MF; ++j) {
    const int chunk = j * 256 + tid;
    const int r = chunk >> 3, c = chunk & 7;
    const int cs = c ^ (r & 7);
    GLOAD_LDS16(A + (size_t)(row0 + r) * K + k0 + cs * 8, sA + chunk * 8);
  }
#pragma unroll
  for (int j = 0; j < 4; ++j) {
    const int chunk = j * 256 + tid;
    const int r = chunk >> 3, c = chunk & 7;
    const int cs = c ^ (r & 7);
    GLOAD_LDS16(BT + (size_t)(col0 + r) * K + k0 + cs * 8, sB + chunk * 8);
  }
}

template <int EPI, int BM>
__global__ __launch_bounds__(256) void gemm_bt(
    const bf16_t* __restrict__ A, const bf16_t* __restrict__ BT,
    const float* __restrict__ bias, const float* __restrict__ res,
    const float* __restrict__ prelu, float* __restrict__ outf,
    bf16_t* __restrict__ ob0, bf16_t* __restrict__ ob1, bf16_t* __restrict__ ob2,
    int K, int N) {
  constexpr int MF = BM / 32;  // m-fragments per wave; also A chunks/thread
  __shared__ __align__(16) bf16_t sA[2][BM * 64];
  __shared__ __align__(16) bf16_t sB[2][128 * 64];
  const int tid = threadIdx.x;
  const int lane = tid & 63;
  const int w = tid >> 6;
  const int wr = w >> 1, wc = w & 1;
  const int row0 = blockIdx.x * BM, col0 = blockIdx.y * 128;

  f32x4 acc[MF][4] = {};

  stage_tile<MF>(A, BT, K, row0, col0, 0, sA[0], sB[0], tid);
  __syncthreads();

  const int nk = K >> 6;
  for (int t = 0; t < nk; ++t) {
    const int cur = t & 1;
    if (t + 1 < nk)
      stage_tile<MF>(A, BT, K, row0, col0, (t + 1) * 64, sA[cur ^ 1], sB[cur ^ 1], tid);
    const bf16_t* __restrict__ pA = sA[cur];
    const bf16_t* __restrict__ pB = sB[cur];
#pragma unroll
    for (int kk = 0; kk < 2; ++kk) {
      bfx8 af[MF], bfr[4];
#pragma unroll
      for (int m = 0; m < MF; ++m) {
        const int r = wr * (BM / 2) + m * 16 + (lane & 15);
        const int c = (kk * 4 + (lane >> 4)) ^ (r & 7);
        af[m] = *reinterpret_cast<const bfx8*>(pA + r * 64 + c * 8);
      }
#pragma unroll
      for (int n = 0; n < 4; ++n) {
        const int r = wc * 64 + n * 16 + (lane & 15);
        const int c = (kk * 4 + (lane >> 4)) ^ (r & 7);
        bfr[n] = *reinterpret_cast<const bfx8*>(pB + r * 64 + c * 8);
      }
#pragma unroll
      for (int m = 0; m < MF; ++m)
#pragma unroll
        for (int n = 0; n < 4; ++n) acc[m][n] = MFMA_BF16(af[m], bfr[n], acc[m][n]);
    }
    __syncthreads();
  }

  const float pa = (EPI == EPI_MLP1) ? prelu[0] : 0.0f;
#pragma unroll
  for (int m = 0; m < MF; ++m) {
#pragma unroll
    for (int n = 0; n < 4; ++n) {
#pragma unroll
      for (int j = 0; j < 4; ++j) {
        const int row = row0 + wr * (BM / 2) + m * 16 + ((lane >> 4) << 2) + j;
        const int col = col0 + wc * 64 + n * 16 + (lane & 15);
        const float v = acc[m][n][j];
        if (EPI == EPI_QKV) {
          const int sel = col >> 10;
          const int h = (col >> 6) & 15, d = col & 63;
          const int bb = row >> 10, t = row & 1023;
          bf16_t* dst = (sel == 0) ? ob0 : (sel == 1) ? ob1 : ob2;
          dst[((size_t)(bb * 16 + h) * 1024 + t) * 64 + d] = (bf16_t)v;
        } else if (EPI == EPI_MLP1) {
          float t = v + bias[col];
          t = (t > 0.0f) ? t : pa * t;
          ob0[(size_t)row * N + col] = (bf16_t)t;
        } else {  // EPI_WO / EPI_FINAL
          outf[(size_t)row * N + col] = v + bias[col] + res[(size_t)row * N + col];
        }
      }
    }
  }
}

// ---------------- Causal flash attention ----------------
__global__ __launch_bounds__(256) void attn_kernel(const bf16_t* __restrict__ kproj,
                                                   const bf16_t* __restrict__ qproj,
                                                   const bf16_t* __restrict__ vproj,
                                                   bf16_t* __restrict__ att) {
  __shared__ __align__(16) bf16_t sK[2][64 * 64];
  __shared__ __align__(16) bf16_t sVt[2][64 * 64];
  __shared__ __align__(16) bf16_t sP[4][16 * 64];
  const int tid = threadIdx.x, lane = tid & 63, w = tid >> 6;
  const int g = lane >> 4, l15 = lane & 15;
  const int bh = blockIdx.y;
  const size_t head = (size_t)bh * (1024 * 64);
  const int b = bh >> 4, h = bh & 15;
  const int vrow = 2 * (tid >> 3);
  const int vdb = tid & 7;

  for (int half = 0; half < 2; ++half) {
    const int tb = half ? (15 - (int)blockIdx.x) : (int)blockIdx.x;
    const int t0 = tb * 64;
    const int nsb = tb + 1;

    __syncthreads();

    bfx8 aq0, aq1;
    {
      const bf16_t* qrow = kproj + head + (size_t)(t0 + w * 16 + l15) * 64 + g * 8;
      aq0 = *reinterpret_cast<const bfx8*>(qrow);
      aq1 = *reinterpret_cast<const bfx8*>(qrow + 32);
    }

    {
#pragma unroll
      for (int j = 0; j < 2; ++j) {
        const int chunk = j * 256 + tid;
        const int r = chunk >> 3, c = chunk & 7;
        const int cs = c ^ (r & 7);
        GLOAD_LDS16(qproj + head + (size_t)r * 64 + cs * 8, sK[0] + chunk * 8);
      }
      const bf16_t* vp = vproj + head + (size_t)vrow * 64 + vdb * 8;
      const u16x8 v0 = *reinterpret_cast<const u16x8*>(vp);
      const u16x8 v1 = *reinterpret_cast<const u16x8*>(vp + 64);
#pragma unroll
      for (int i = 0; i < 8; ++i) {
        const int d = vdb * 8 + i;
        const int cc = ((vrow >> 3) ^ i ^ vdb) & 7;
        const u32 pk = ((u32)v1[i] << 16) | (u32)v0[i];
        *reinterpret_cast<u32*>(sVt[0] + d * 64 + cc * 8 + (vrow & 7)) = pk;
      }
    }
    __syncthreads();

    f32x4 accO[4] = {};
    float mrun[4], lrun[4];
#pragma unroll
    for (int j = 0; j < 4; ++j) {
      mrun[j] = -1e30f;
      lrun[j] = 0.0f;
    }

    for (int sb = 0; sb < nsb; ++sb) {
      const int cur = sb & 1;
      const bool pf = (sb + 1 < nsb);
      u16x8 v0n, v1n;
      if (pf) {
        const int s0n = (sb + 1) * 64;
#pragma unroll
        for (int j = 0; j < 2; ++j) {
          const int chunk = j * 256 + tid;
          const int r = chunk >> 3, c = chunk & 7;
          const int cs = c ^ (r & 7);
          GLOAD_LDS16(qproj + head + (size_t)(s0n + r) * 64 + cs * 8, sK[cur ^ 1] + chunk * 8);
        }
        const bf16_t* vp = vproj + head + (size_t)(s0n + vrow) * 64 + vdb * 8;
        v0n = *reinterpret_cast<const u16x8*>(vp);
        v1n = *reinterpret_cast<const u16x8*>(vp + 64);
      }

      f32x4 accS[4] = {};
      const bf16_t* sKc = sK[cur];
#pragma unroll
      for (int kk = 0; kk < 2; ++kk) {
        const bfx8 aq = kk ? aq1 : aq0;
#pragma unroll
        for (int n = 0; n < 4; ++n) {
          const int r = n * 16 + l15;
          const int c = (kk * 4 + g) ^ (r & 7);
          const bfx8 bk = *reinterpret_cast<const bfx8*>(sKc + r * 64 + c * 8);
          accS[n] = MFMA_BF16(aq, bk, accS[n]);
        }
      }

      const int rbase = t0 + w * 16 + (g << 2);
      const int cbase = sb * 64 + l15;
#pragma unroll
      for (int j = 0; j < 4; ++j) {
        const int t = rbase + j;
        float mx = -1e30f;
#pragma unroll
        for (int n = 0; n < 4; ++n) {
          float v = accS[n][j] * 0.03125f;
          v = ((cbase + n * 16) <= t) ? v : -1e30f;
          accS[n][j] = v;
          mx = fmaxf(mx, v);
        }
        mx = fmaxf(mx, __shfl_xor(mx, 1));
        mx = fmaxf(mx, __shfl_xor(mx, 2));
        mx = fmaxf(mx, __shfl_xor(mx, 4));
        mx = fmaxf(mx, __shfl_xor(mx, 8));
        const float mnew = fmaxf(mrun[j], mx);
        const float al = __expf(mrun[j] - mnew);
        float rsum = 0.0f;
#pragma unroll
        for (int n = 0; n < 4; ++n) {
          const float p = __expf(accS[n][j] - mnew);
          accS[n][j] = p;
          rsum += p;
        }
        rsum += __shfl_xor(rsum, 1);
        rsum += __shfl_xor(rsum, 2);
        rsum += __shfl_xor(rsum, 4);
        rsum += __shfl_xor(rsum, 8);
        lrun[j] = lrun[j] * al + rsum;
        mrun[j] = mnew;
#pragma unroll
        for (int n = 0; n < 4; ++n) accO[n][j] *= al;
      }

      bf16_t* sPw = sP[w];
#pragma unroll
      for (int n = 0; n < 4; ++n)
#pragma unroll
        for (int j = 0; j < 4; ++j) {
          const int r = (g << 2) + j;
          const int s = n * 16 + l15;
          const int cc = (s >> 3) ^ (r & 7);
          sPw[r * 64 + cc * 8 + (s & 7)] = (bf16_t)accS[n][j];
        }

      const bf16_t* sVc = sVt[cur];
#pragma unroll
      for (int kk = 0; kk < 2; ++kk) {
        bfx8 ap;
        {
          const int r = l15;
          const int c = (kk * 4 + g) ^ (r & 7);
          ap = *reinterpret_cast<const bfx8*>(sPw + r * 64 + c * 8);
        }
#pragma unroll
        for (int n = 0; n < 4; ++n) {
          const int d = n * 16 + l15;
          const int c = (kk * 4 + g) ^ (d & 7) ^ ((d >> 3) & 7);
          const bfx8 bv = *reinterpret_cast<const bfx8*>(sVc + d * 64 + c * 8);
          accO[n] = MFMA_BF16(ap, bv, accO[n]);
        }
      }

      if (pf) {
#pragma unroll
        for (int i = 0; i < 8; ++i) {
          const int d = vdb * 8 + i;
          const int cc = ((vrow >> 3) ^ i ^ vdb) & 7;
          const u32 pk = ((u32)v1n[i] << 16) | (u32)v0n[i];
          *reinterpret_cast<u32*>(sVt[cur ^ 1] + d * 64 + cc * 8 + (vrow & 7)) = pk;
        }
      }
      __syncthreads();
    }

#pragma unroll
    for (int j = 0; j < 4; ++j) {
      const float inv = 1.0f / lrun[j];
      const int t = t0 + w * 16 + (g << 2) + j;
#pragma unroll
      for (int n = 0; n < 4; ++n) {
        const int d = n * 16 + l15;
        att[((size_t)(b * 1024 + t)) * 1024 + h * 64 + d] = (bf16_t)(accO[n][j] * inv);
      }
    }
  }
}

extern "C" void kernel_launch(void* const* d_in, const int* in_sizes, int n_in,
                              void* d_out, int out_size, void* d_ws, size_t ws_size,
                              hipStream_t stream) {
  (void)in_sizes; (void)n_in; (void)out_size; (void)ws_size;
  const float* x = (const float*)d_in[0];
  const float* ln1w = (const float*)d_in[1];
  const float* ln1b = (const float*)d_in[2];
  const float* Wk = (const float*)d_in[3];
  const float* Wq = (const float*)d_in[4];
  const float* Wv = (const float*)d_in[5];
  const float* Wo = (const float*)d_in[6];
  const float* bo = (const float*)d_in[7];
  const float* ln2w = (const float*)d_in[8];
  const float* ln2b = (const float*)d_in[9];
  const float* W1 = (const float*)d_in[10];
  const float* b1 = (const float*)d_in[11];
  const float* pa = (const float*)d_in[12];
  const float* W2 = (const float*)d_in[13];
  const float* b2 = (const float*)d_in[14];
  float* out = (float*)d_out;
  char* ws = (char*)d_ws;
  const size_t MB = 1ull << 20;
  bf16_t* h1 = (bf16_t*)(ws + 0 * MB);      // [4096,1024]
  bf16_t* h2 = (bf16_t*)(ws + 8 * MB);      // [4096,1024]
  bf16_t* qb = (bf16_t*)(ws + 16 * MB);     // [B*H,1024,64]
  bf16_t* kb = (bf16_t*)(ws + 24 * MB);
  bf16_t* vb = (bf16_t*)(ws + 32 * MB);
  bf16_t* attb = (bf16_t*)(ws + 40 * MB);   // [4096,1024]
  bf16_t* fbuf = (bf16_t*)(ws + 48 * MB);   // [4096,4096]
  bf16_t* WqkvT = (bf16_t*)(ws + 80 * MB);  // [3072,1024]
  bf16_t* WoT = (bf16_t*)(ws + 86 * MB);    // [1024,1024]
  bf16_t* W1T = (bf16_t*)(ws + 88 * MB);    // [4096,1024]
  bf16_t* W2T = (bf16_t*)(ws + 96 * MB);    // [1024,4096]

  transpose_qkv<<<dim3(16, 48), 256, 0, stream>>>(Wq, Wk, Wv, WqkvT);
  transpose_cast<<<dim3(16, 16), 256, 0, stream>>>(Wo, WoT, 1024, 1024);
  transpose_cast<<<dim3(16, 64), 256, 0, stream>>>(W1, W1T, 1024, 4096);
  transpose_cast<<<dim3(64, 16), 256, 0, stream>>>(W2, W2T, 4096, 1024);

  ln_kernel<<<4096, 256, 0, stream>>>(x, ln1w, ln1b, h1);
  gemm_bt<EPI_QKV, 128><<<dim3(32, 24), 256, 0, stream>>>(h1, WqkvT, nullptr, nullptr,
                                                          nullptr, nullptr, qb, kb, vb,
                                                          1024, 3072);
  attn_kernel<<<dim3(8, 64), 256, 0, stream>>>(kb, qb, vb, attb);
  gemm_bt<EPI_WO, 64><<<dim3(64, 8), 256, 0, stream>>>(attb, WoT, bo, x, nullptr, out,
                                                       nullptr, nullptr, nullptr, 1024, 1024);
  ln_kernel<<<4096, 256, 0, stream>>>(out, ln2w, ln2b, h2);
  gemm_bt<EPI_MLP1, 128><<<dim3(32, 32), 256, 0, stream>>>(h2, W1T, b1, nullptr, pa, nullptr,
                                                           fbuf, nullptr, nullptr, 1024, 4096);
  gemm_bt<EPI_FINAL, 64><<<dim3(64, 8), 256, 0, stream>>>(fbuf, W2T, b2, out, nullptr, out,
                                                          nullptr, nullptr, nullptr, 4096, 1024);
}